// Round 4
// baseline (222.247 us; speedup 1.0000x reference)
//
#include <hip/hip_runtime.h>

// ---------------------------------------------------------------------------
// Conv2DQwenRMSNorm: y = x @ W^T, W = mean_l(conv_w); RMSNorm(y)*norm_w.
// B=4,S=4096 -> M=16384; H=1024 (N=K).
//
// R7: straggler-limited theory (256 blocks on 256 CUs, 1-resident => any CU
// with 2 blocks runs 2x serial ~= the measured 64us; occ 18.8% < 25%).
// Fix: MTILE 64->32, 512 blocks, LDS 64KB => 2 blocks RESIDENT per CU:
//  - imbalance quantum halves AND a 3rd block overlaps concurrently
//  - co-resident blocks overlap stage/K-loop/epilogue phases for free
//  - 8 waves x (32 rows x 128 cols), acc 4x16=64 VGPR, depth-2 A/B FIFO,
//    launch_bounds(512,4) caps VGPR at 128 for 4 waves/SIMD
// Cost accepted: aggregate B-from-L2 doubles to 1 GB (~29us floor) < 64us.
// ---------------------------------------------------------------------------

using bf16x8 = __attribute__((ext_vector_type(8))) short;
using f32x16 = __attribute__((ext_vector_type(16))) float;
using f32x4  = __attribute__((ext_vector_type(4))) float;

#define NDIM 1024
#define MTILE 32

__device__ __forceinline__ unsigned short f2bf(float f) {
    unsigned u = __float_as_uint(f);
    u += 0x7fffu + ((u >> 16) & 1u);          // RNE
    return (unsigned short)(u >> 16);
}

// ---- Kernel 1: W = mean_l conv_w, bf16, fragment-major ---------------------
__global__ __launch_bounds__(256) void wprep_kernel(const float* __restrict__ cw,
                                                    unsigned short* __restrict__ Wf) {
    const int idx = blockIdx.x * 256 + threadIdx.x;  // 0..262143
    const int o   = idx >> 8;                        // row 0..1023
    const int q   = idx & 255;                       // float4 index in row
    const float* p = cw + (size_t)o * NDIM + (q << 2);
    f32x4 s = {0.f, 0.f, 0.f, 0.f};
#pragma unroll
    for (int l = 0; l < 20; ++l) {
        f32x4 v = __builtin_nontemporal_load((const f32x4*)(p + (size_t)l * (NDIM * NDIM)));
        s += v;
    }
    const float sc = 0.05f;                          // 1/L
    ushort4 o4;
    o4.x = f2bf(s[0] * sc); o4.y = f2bf(s[1] * sc);
    o4.z = f2bf(s[2] * sc); o4.w = f2bf(s[3] * sc);
    const int ct  = o >> 5, ml = o & 31;
    const int k16 = q >> 2, h = (q >> 1) & 1, half = q & 1;
    // frag-major: frag(ct,k16)=1KB; slot lane=(h*32+ml) holds W[ct*32+ml][k16*16+h*8..+7]
    *(ushort4*)((char*)Wf + (((ct << 6) + k16) << 10) + (((h << 5) + ml) << 4) + (half << 3)) = o4;
}

// ---- Kernel 2: fused GEMM + RMSNorm ---------------------------------------
__global__ __launch_bounds__(512, 4) void gemm_rms_kernel(
        const float* __restrict__ x, const unsigned short* __restrict__ Wf,
        const float* __restrict__ nw, float* __restrict__ out) {
    __shared__ short lAf[MTILE * NDIM];              // 64 KB, frag-major
    __shared__ float rowss[MTILE];

    const int tid  = threadIdx.x;
    const int wv   = tid >> 6;                       // 0..7
    const int lane = tid & 63;
    const int ml   = lane & 31;
    const int h    = lane >> 5;
    const int row0 = blockIdx.x * MTILE;
    const int phase = (blockIdx.x * 37) & 63;        // L2 decorrelation

    if (tid < MTILE) rowss[tid] = 0.f;

    // ---- stage A panel: 32 rows x 1024 k, fp32->bf16, frag-major + swizzle --
    {
        const int row = tid >> 4;                    // 0..31 (16 thr/row)
        const float* xr = x + (size_t)(row0 + row) * NDIM;
#pragma unroll
        for (int it = 0; it < 8; ++it) {
            const int k0 = ((tid & 15) << 3) + (it << 7);  // 8-elem chunk base
            f32x4 v0 = __builtin_nontemporal_load((const f32x4*)(xr + k0));
            f32x4 v1 = __builtin_nontemporal_load((const f32x4*)(xr + k0 + 4));
            bf16x8 c8;
            c8[0] = (short)f2bf(v0[0]); c8[1] = (short)f2bf(v0[1]);
            c8[2] = (short)f2bf(v0[2]); c8[3] = (short)f2bf(v0[3]);
            c8[4] = (short)f2bf(v1[0]); c8[5] = (short)f2bf(v1[1]);
            c8[6] = (short)f2bf(v1[2]); c8[7] = (short)f2bf(v1[3]);
            const int k16 = k0 >> 4, hh = (k0 >> 3) & 1;
            const int slot = ((hh << 5) + row) ^ (k16 & 7);
            *(bf16x8*)((char*)lAf + (k16 << 10) + (slot << 4)) = c8;
        }
    }
    __syncthreads();

    // ---- K loop: depth-2 A/B register FIFO, consume-then-refill, no bar ----
    // wave wv owns column-tiles ct = wv*4 .. wv*4+3 (128 cols)
    const char* wB = (const char*)Wf + ((size_t)wv << 18) + (lane << 4);

    f32x16 acc[4];
#pragma unroll
    for (int tc = 0; tc < 4; ++tc)
#pragma unroll
        for (int r = 0; r < 16; ++r) acc[tc][r] = 0.f;

    bf16x8 af[2], bfr[2][4];
#pragma unroll
    for (int d = 0; d < 2; ++d) {
        const int k = (d + phase) & 63;
#pragma unroll
        for (int c = 0; c < 4; ++c)
            bfr[d][c] = *(const bf16x8*)(wB + (c << 16) + (k << 10));
        af[d] = *(const bf16x8*)((const char*)lAf + (k << 10) + ((lane ^ (k & 7)) << 4));
    }

#pragma unroll 4
    for (int i = 0; i < 64; ++i) {
        const int ab = i & 1;
        __builtin_amdgcn_s_setprio(1);
        acc[0] = __builtin_amdgcn_mfma_f32_32x32x16_bf16(af[ab], bfr[ab][0], acc[0], 0, 0, 0);
        acc[1] = __builtin_amdgcn_mfma_f32_32x32x16_bf16(af[ab], bfr[ab][1], acc[1], 0, 0, 0);
        acc[2] = __builtin_amdgcn_mfma_f32_32x32x16_bf16(af[ab], bfr[ab][2], acc[2], 0, 0, 0);
        acc[3] = __builtin_amdgcn_mfma_f32_32x32x16_bf16(af[ab], bfr[ab][3], acc[3], 0, 0, 0);
        __builtin_amdgcn_s_setprio(0);
        if (i + 2 < 64) {
            const int kn = (i + 2 + phase) & 63;
#pragma unroll
            for (int c = 0; c < 4; ++c)
                bfr[ab][c] = *(const bf16x8*)(wB + (c << 16) + (kn << 10));
            af[ab] = *(const bf16x8*)((const char*)lAf + (kn << 10) +
                                      ((lane ^ (kn & 7)) << 4));
        }
    }

    // ---- epilogue: fused RMSNorm ----
    // C/D layout (32x32): col = lane&31, row = (r&3) + 8*(r>>2) + 4*(lane>>5)
#pragma unroll
    for (int r = 0; r < 16; ++r) {
        float v = 0.f;
#pragma unroll
        for (int tc = 0; tc < 4; ++tc) { float a = acc[tc][r]; v += a * a; }
#pragma unroll
        for (int m = 1; m <= 16; m <<= 1) v += __shfl_xor(v, m, 64);
        if (ml == 0)
            atomicAdd(&rowss[(r & 3) + 8 * (r >> 2) + 4 * h], v);
    }
    __syncthreads();
    if (tid < MTILE) rowss[tid] = rsqrtf(rowss[tid] * (1.0f / 1024.0f) + 1e-6f);
    __syncthreads();

    float nwv[4];
#pragma unroll
    for (int tc = 0; tc < 4; ++tc) nwv[tc] = nw[(wv << 7) + tc * 32 + ml];

#pragma unroll
    for (int r = 0; r < 16; ++r) {
        const int m = (r & 3) + 8 * (r >> 2) + 4 * h;
        const float rs = rowss[m];
        float* orow = out + (size_t)(row0 + m) * NDIM + (wv << 7) + ml;
#pragma unroll
        for (int tc = 0; tc < 4; ++tc)
            __builtin_nontemporal_store(acc[tc][r] * rs * nwv[tc], orow + tc * 32);
    }
}

extern "C" void kernel_launch(void* const* d_in, const int* in_sizes, int n_in,
                              void* d_out, int out_size, void* d_ws, size_t ws_size,
                              hipStream_t stream) {
    const float* x  = (const float*)d_in[0];
    const float* cw = (const float*)d_in[1];
    const float* nw = (const float*)d_in[2];
    float* out = (float*)d_out;
    unsigned short* Wf = (unsigned short*)d_ws;   // 2 MB fragment-major W

    hipLaunchKernelGGL(wprep_kernel, dim3(1024), dim3(256), 0, stream, cw, Wf);
    hipLaunchKernelGGL(gemm_rms_kernel, dim3(512), dim3(512), 0, stream, x, Wf, nw, out);
}